// Round 18
// baseline (200.149 us; speedup 1.0000x reference)
//
#include <hip/hip_runtime.h>
#include <hip/hip_fp16.h>

typedef unsigned int uint32;
using half2v  = __attribute__((ext_vector_type(2))) _Float16;
using half4v  = __attribute__((ext_vector_type(4))) _Float16;
using half8   = __attribute__((ext_vector_type(8))) _Float16;
using floatx4 = __attribute__((ext_vector_type(4))) float;

__device__ __forceinline__ float sigm_f(float x){
  return __builtin_amdgcn_rcpf(1.0f + __expf(-x));
}
__device__ __forceinline__ float silu_f(float x){ return x * sigm_f(x); }

__device__ __forceinline__ half2v pkrtz(float a, float b){
  return __builtin_bit_cast(half2v, __builtin_amdgcn_cvt_pkrtz(a, b));
}

// packed fp16 silu: 2 elements; overflow is graceful (exp->inf->rcp->0).
__device__ __forceinline__ half2v silu_h2(half2v v){
  __half2 hv = __builtin_bit_cast(__half2, v);
  __half2 e  = h2exp(__hneg2(hv));
  __half2 r  = h2rcp(__hadd2(e, __float2half2_rn(1.0f)));
  return __builtin_bit_cast(half2v, __hmul2(hv, r));
}

// async global->LDS, 16B per lane, zero VGPR cost. dst is wave-uniform base;
// HW writes lane i at dst + i*16B. src is per-lane. Respects exec mask.
__device__ __forceinline__ void gll16(const _Float16* src, _Float16* ldsDst){
  __builtin_amdgcn_global_load_lds(
      (const __attribute__((address_space(1))) uint32*)src,
      (__attribute__((address_space(3))) uint32*)ldsDst, 16, 0, 0);
}

// ---------------------------------------------------------------------------
// fp16 weight blob layout (element offsets):
//   0      stemW0..2 | 86016 w1 (cls/reg) | 196608 w2 | 307200 clsp_w
//   330240 wdT | 340608 regobj | 345216 dwbias | 346368 total
// ---------------------------------------------------------------------------
#define OFF_W1    86016
#define OFF_W2    196608
#define OFF_HEAD  307200
#define OFF_WDT   330240
#define OFF_ROBJ  340608
#define OFF_DWB   345216
#define WTOT      346368

// stem output, CHANNEL-GROUP-MAJOR: [g=12][n=134400][8ch]
#define NDW  134400

__global__ __launch_bounds__(256) void wconv_k(
    const float* __restrict__ s0, const float* __restrict__ s1,
    const float* __restrict__ s2, const float* __restrict__ cw1,
    const float* __restrict__ rw1, const float* __restrict__ cw2,
    const float* __restrict__ rw2, const float* __restrict__ chw,
    const float* __restrict__ cwd, const float* __restrict__ rwd,
    const float* __restrict__ rpw, const float* __restrict__ opw,
    const float* __restrict__ cbd, const float* __restrict__ rbd,
    _Float16* __restrict__ dst)
{
  int i = blockIdx.x*256 + threadIdx.x;
  if (i >= WTOT) return;
  float v;
  if (i < OFF_WDT) {
    const float* p; int off;
    if      (i < 12288)  { p = s0;  off = i; }
    else if (i < 36864)  { p = s1;  off = i - 12288; }
    else if (i < 86016)  { p = s2;  off = i - 36864; }
    else if (i < 141312) { p = cw1; off = i - 86016; }
    else if (i < 196608) { p = rw1; off = i - 141312; }
    else if (i < 251904) { p = cw2; off = i - 196608; }
    else if (i < 307200) { p = rw2; off = i - 251904; }
    else                 { p = chw; off = i - 307200; }
    v = p[off];
  } else if (i < OFF_ROBJ) {
    int rel = i - OFF_WDT;
    int br = rel / 5184; int r2 = rel - br*5184;
    int lvl = r2 / 1728; int r3 = r2 - lvl*1728;
    int j = r3 / 192;    int c = r3 - j*192;
    const float* wd = br ? rwd : cwd;
    v = wd[lvl*1728 + c*9 + j];
  } else if (i < OFF_DWB) {
    int rel = i - OFF_ROBJ;
    int lvl = rel / 1536; int r2 = rel - lvl*1536;
    int co = r2 / 96;     int k = r2 - co*96;
    v = (co < 4) ? rpw[lvl*384 + co*96 + k] : (co == 4 ? opw[lvl*96 + k] : 0.f);
  } else {
    int rel = i - OFF_DWB;
    int br = rel / 576;  int r2 = rel - br*576;
    int lvl = r2 / 192;  int c = r2 - lvl*192;
    v = (br ? rbd : cbd)[lvl*192 + c];
  }
  dst[i] = (_Float16)v;
}

// ---------------------------------------------------------------------------
// Stem GEMM from NCHW fp32, fp16 MFMA. Output CHANNEL-GROUP-MAJOR [g][n][8].
// ---------------------------------------------------------------------------
__global__ __launch_bounds__(256) void stem_k(
    const float* __restrict__ x0, const float* __restrict__ x1,
    const float* __restrict__ x2, const _Float16* __restrict__ Wb,
    const float* __restrict__ sb0, const float* __restrict__ sb1,
    const float* __restrict__ sb2, _Float16* __restrict__ Out)
{
  const int m0 = blockIdx.x << 7;
  const int lvl = (m0 < 102400) ? 0 : (m0 < 128000 ? 1 : 2);
  const int CIN = (lvl==0)?128:(lvl==1?256:512);
  const int HW  = (lvl==0)?6400:(lvl==1?1600:400);
  const int noff= (lvl==0)?0:(lvl==1?102400:128000);
  const float* X = (lvl==0)?x0:(lvl==1?x1:x2);
  const _Float16* Wl = Wb + ((lvl==0)?0:(lvl==1?12288:36864));
  const float* bias = (lvl==0)?sb0:(lvl==1?sb1:sb2);

  int t=threadIdx.x, lane=t&63, wv=t>>6, mr=lane&15, quad=lane>>4;

  int idx[2];
  #pragma unroll
  for (int nt=0; nt<2; ++nt) {
    int n = m0 + wv*32 + nt*16 + mr;
    int m = n - noff; int b_ = m / HW; int p = m - b_*HW;
    idx[nt] = (b_*CIN + quad*8)*HW + p;
  }
  const _Float16* Ap = Wl + mr*CIN + quad*8;

  floatx4 zero = {0.f,0.f,0.f,0.f};
  floatx4 acc[6][2];
  #pragma unroll
  for (int i=0;i<6;++i)
    #pragma unroll
    for (int j=0;j<2;++j) acc[i][j] = zero;

  for (int k=0; k<CIN; k+=32) {
    half8 a[6], b[2];
    #pragma unroll
    for (int mt=0; mt<6; ++mt) a[mt] = *(const half8*)(Ap + mt*16*CIN);
    #pragma unroll
    for (int nt=0; nt<2; ++nt) {
      float f[8];
      #pragma unroll
      for (int j=0;j<8;++j) f[j] = X[idx[nt] + j*HW];
      half2v* bh = (half2v*)&b[nt];
      #pragma unroll
      for (int j=0;j<4;++j) bh[j] = pkrtz(f[2*j], f[2*j+1]);
    }
    #pragma unroll
    for (int mt=0; mt<6; ++mt)
      #pragma unroll
      for (int nt=0; nt<2; ++nt)
        acc[mt][nt] = __builtin_amdgcn_mfma_f32_16x16x32_f16(a[mt], b[nt], acc[mt][nt], 0, 0, 0);
    Ap += 32;
    #pragma unroll
    for (int nt=0; nt<2; ++nt) idx[nt] += 32*HW;
  }

  #pragma unroll
  for (int mt=0; mt<6; ++mt) {
    float4 bv = *(const float4*)(bias + mt*16 + quad*4);
    int co = mt*16 + quad*4;
    int g = co >> 3; int h = co & 7;
    #pragma unroll
    for (int nt=0; nt<2; ++nt) {
      int pos = m0 + wv*32 + nt*16 + mr;
      half4v o;
      o[0] = (_Float16)silu_f(acc[mt][nt][0] + bv.x);
      o[1] = (_Float16)silu_f(acc[mt][nt][1] + bv.y);
      o[2] = (_Float16)silu_f(acc[mt][nt][2] + bv.z);
      o[3] = (_Float16)silu_f(acc[mt][nt][3] + bv.w);
      *(half4v*)(Out + g*NDW*8 + pos*8 + h) = o;
    }
  }
}

// ---------------------------------------------------------------------------
// MEGAFUSED v5 (r17 + split phase 2):
//  2a: dw conv for this thread's 6 k-slices (pure LDS+VALU) -> af_all[6] regs
//  2b: proj GEMM streams W2 global loads under 36 MFMA with NO intervening
//      VALU deps -- the compiler can issue all loads ahead (GEMM inner-loop
//      shape). Removes the last global-latency rounds from the k-body.
// LDS: wdl 1984 + halo 24*808 = 42.7KB -> 3 blocks/CU; ldsP aliases halo.
// grid (2144, 2): [0,1600) lvl0, [1600,2000) lvl1, [2000,2144) lvl2
// (overlapping 8x8 tiles on 20x20, y0,x0 in {0,6,12}; dup writes identical).
// ---------------------------------------------------------------------------
#define PSTRIDE 104
#define HS2 808
__global__ __launch_bounds__(256, 3) void xfuse_k(
    const _Float16* __restrict__ stemO, const _Float16* __restrict__ wbf,
    const float* __restrict__ b1c, const float* __restrict__ b1r,
    const float* __restrict__ b2_c, const float* __restrict__ b2_r,
    const float* __restrict__ hb, const float* __restrict__ rb,
    const float* __restrict__ ob, float* __restrict__ out)
{
  __shared__ _Float16 wdl[1984];         // dw weights [tap][192] | bias [192]
  __shared__ _Float16 halo[24*HS2];      // [g][100 entries][8ch] (+pad)
  _Float16* ldsP = halo;                 // alias after phase-2 barrier
  const int bz = blockIdx.y;
  const float* b2 = bz ? b2_r : b2_c;

  int orig = blockIdx.x;
  int bx = (orig & 7)*268 + (orig >> 3);   // bijective: 2144 = 8*268

  int lvl, W, HW, noff, a0;
  int b_, y0, x0;
  if (bx < 1600) {
    lvl = 0; W = 80; HW = 6400; noff = 0;      a0 = 0;
    b_ = bx / 100; int tl = bx - b_*100;
    y0 = (tl / 10) * 8; x0 = (tl - (tl/10)*10) * 8;
  } else if (bx < 2000) {
    lvl = 1; W = 40; HW = 1600; noff = 102400; a0 = 6400;
    int rel = bx - 1600; b_ = rel / 25; int tl = rel - b_*25;
    y0 = (tl / 5) * 8; x0 = (tl - (tl/5)*5) * 8;
  } else {
    lvl = 2; W = 20; HW = 400; noff = 128000; a0 = 8000;
    int rel = bx - 2000; b_ = rel / 9; int tl = rel - b_*9;
    int iy = tl / 3; int ix = tl - iy*3;
    y0 = iy*6; x0 = ix*6;                 // overlapping 8x8 tiles on 20x20
  }

  int t = threadIdx.x, lane = t & 63, wv = t >> 6;
  int mr = lane & 15, quad = lane >> 4;
  const int p = wv*16 + mr;              // this thread's tile-local position

  const _Float16* wT = wbf + OFF_WDT + bz*5184 + lvl*1728;
  const _Float16* bB = wbf + OFF_DWB + bz*576 + lvl*192;
  const _Float16* Ap = wbf + OFF_W2 + bz*55296 + lvl*18432 + mr*192 + quad*8;

  // ---- 0. stage dw weights+bias (1920 hw = 240 x 16B) into LDS, async ----
  {
    if (wv < 3) {
      gll16(wT + (wv*64 + lane)*8, wdl + wv*512);
    } else {
      if (lane < 24)
        gll16(wT + (192 + lane)*8, wdl + 1536);          // wdT chunks 192..215
      else if (lane < 48)
        gll16(bB + (lane - 24)*8, wdl + 1536);           // bias -> 1728..1919
    }
  }

  // this thread's global position n (center tile)
  const int n = noff + b_*HW + (y0 + (p>>3))*W + x0 + (p&7);

  // resid prefetch (consumed after phase 2)
  half4v rsv[6];
  #pragma unroll
  for (int mt=0; mt<6; ++mt) {
    int co = mt*16 + quad*4;
    int g = co >> 3; int h = co & 7;
    rsv[mt] = *(const half4v*)(stemO + g*(NDW*8) + n*8 + h);
  }

  // ---- 1. expand GEMM: W1 (reg-hoisted) x stem (direct global) -> halo ----
  {
    const _Float16* W1 = wbf + OFF_W1 + bz*55296 + lvl*18432;
    const float* bp1 = (bz ? b1r : b1c) + lvl*192;
    // hoist A-frags: 3 M-tiles x 3 k-steps
    half8 wf[3][3];
    #pragma unroll
    for (int m3 = 0; m3 < 3; ++m3)
      #pragma unroll
      for (int ks = 0; ks < 3; ++ks)
        wf[m3][ks] = *(const half8*)(W1 + ((wv*3+m3)*16 + mr)*96 + ks*32 + quad*8);

    #pragma unroll
    for (int nt = 0; nt < 7; ++nt) {
      int ee = nt*16 + mr;
      int e = ee < 100 ? ee : 99;
      int hy = e / 10, hx = e - hy*10;
      int ay = y0 - 1 + hy, ax = x0 - 1 + hx;
      bool oob = ((unsigned)ay >= (unsigned)W) || ((unsigned)ax >= (unsigned)W);
      int yy = ay < 0 ? 0 : (ay >= W ? W-1 : ay);
      int xx = ax < 0 ? 0 : (ax >= W ? W-1 : ax);
      int ne = noff + b_*HW + yy*W + xx;

      floatx4 acc[3];
      #pragma unroll
      for (int m3 = 0; m3 < 3; ++m3) acc[m3] = floatx4{0.f,0.f,0.f,0.f};
      #pragma unroll
      for (int ks = 0; ks < 3; ++ks) {
        half8 af = *(const half8*)(stemO + (ks*4+quad)*(NDW*8) + ne*8);
        #pragma unroll
        for (int m3 = 0; m3 < 3; ++m3)
          acc[m3] = __builtin_amdgcn_mfma_f32_16x16x32_f16(wf[m3][ks], af, acc[m3], 0, 0, 0);
      }
      if (ee < 100) {
        #pragma unroll
        for (int m3 = 0; m3 < 3; ++m3) {
          int co = (wv*3+m3)*16 + quad*4;
          float4 bv = *(const float4*)(bp1 + co);
          half4v o;
          if (oob) {
            o[0]=o[1]=o[2]=o[3]=(_Float16)0.f;
          } else {
            half2v p01 = silu_h2(pkrtz(acc[m3][0] + bv.x, acc[m3][1] + bv.y));
            half2v p23 = silu_h2(pkrtz(acc[m3][2] + bv.z, acc[m3][3] + bv.w));
            o[0]=p01[0]; o[1]=p01[1]; o[2]=p23[0]; o[3]=p23[1];
          }
          *(half4v*)(halo + (co>>3)*HS2 + ee*8 + (co&7)) = o;
        }
      }
    }
  }
  __syncthreads();   // halo complete + wdl staged (vmcnt drained)

  // ---- 2a. dw conv for this thread's 6 k-slices -> af_all (pure LDS+VALU) --
  half8 af_all[6];
  {
    const int ty = p >> 3, tx = p & 7;
    const _Float16* hb0 = halo + (ty*10 + tx)*8;   // entry (ty,tx) base
    #pragma unroll
    for (int k = 0; k < 6; ++k) {
      const int g = 4*k + quad;
      const _Float16* hg = hb0 + g*HS2;

      half8 a[9], w[9];
      #pragma unroll
      for (int dy = 0; dy < 3; ++dy)
        #pragma unroll
        for (int dx = 0; dx < 3; ++dx)
          a[dy*3+dx] = *(const half8*)(hg + (dy*10 + dx)*8);
      #pragma unroll
      for (int tap = 0; tap < 9; ++tap)
        w[tap] = *(const half8*)(wdl + tap*192 + g*8);
      half8 bv8 = *(const half8*)(wdl + 1728 + g*8);

      half2v ac0 = {bv8[0], bv8[1]};
      half2v ac1 = {bv8[2], bv8[3]};
      half2v ac2 = {bv8[4], bv8[5]};
      half2v ac3 = {bv8[6], bv8[7]};
      #pragma unroll
      for (int tap = 0; tap < 9; ++tap) {
        ac0 += half2v{a[tap][0],a[tap][1]} * half2v{w[tap][0],w[tap][1]};
        ac1 += half2v{a[tap][2],a[tap][3]} * half2v{w[tap][2],w[tap][3]};
        ac2 += half2v{a[tap][4],a[tap][5]} * half2v{w[tap][4],w[tap][5]};
        ac3 += half2v{a[tap][6],a[tap][7]} * half2v{w[tap][6],w[tap][7]};
      }
      half2v* oh = (half2v*)&af_all[k];
      oh[0] = silu_h2(ac0);
      oh[1] = silu_h2(ac1);
      oh[2] = silu_h2(ac2);
      oh[3] = silu_h2(ac3);
    }
  }

  // ---- 2b. proj GEMM: stream W2 under 36 MFMA (no VALU deps) ----
  floatx4 pacc[6];
  #pragma unroll
  for (int j=0;j<6;++j) pacc[j] = floatx4{0.f,0.f,0.f,0.f};
  #pragma unroll
  for (int k = 0; k < 6; ++k) {
    half8 wfp[6];
    #pragma unroll
    for (int mt = 0; mt < 6; ++mt)
      wfp[mt] = *(const half8*)(Ap + mt*16*192 + k*32);
    #pragma unroll
    for (int mt = 0; mt < 6; ++mt)
      pacc[mt] = __builtin_amdgcn_mfma_f32_16x16x32_f16(wfp[mt], af_all[k], pacc[mt], 0, 0, 0);
  }
  __syncthreads();   // halo reads done -> ldsP may overwrite

  // ---- 3. epilogue: + bias + prefetched residual -> ldsP [pos][co] ----
  {
    const float* bp2 = b2 + lvl*96;
    #pragma unroll
    for (int mt=0; mt<6; ++mt) {
      int co = mt*16 + quad*4;
      float4 bv = *(const float4*)(bp2 + co);
      half4v o;
      o[0] = (_Float16)(pacc[mt][0] + bv.x + (float)rsv[mt][0]);
      o[1] = (_Float16)(pacc[mt][1] + bv.y + (float)rsv[mt][1]);
      o[2] = (_Float16)(pacc[mt][2] + bv.z + (float)rsv[mt][2]);
      o[3] = (_Float16)(pacc[mt][3] + bv.w + (float)rsv[mt][3]);
      *(half4v*)(ldsP + p*PSTRIDE + co) = o;
    }
  }
  // heads read only this wave's 16 rows -> no barrier (same-wave ds ordering).

  // ---- heads ----
  if (bz == 0) {
    const _Float16* Bp = wbf + OFF_HEAD + lvl*7680 + mr*96 + quad*8;
    const float* bp = hb + lvl*80;
    floatx4 acc[5];
    #pragma unroll
    for (int j=0;j<5;++j) acc[j] = floatx4{0.f,0.f,0.f,0.f};

    #pragma unroll
    for (int k=0; k<3; ++k) {
      half8 a = *(const half8*)(ldsP + (wv*16 + mr)*PSTRIDE + k*32 + quad*8);
      half8 b[5];
      #pragma unroll
      for (int nt=0; nt<5; ++nt)
        b[nt] = *(const half8*)(Bp + nt*16*96 + k*32);
      #pragma unroll
      for (int nt=0; nt<5; ++nt)
        acc[nt] = __builtin_amdgcn_mfma_f32_16x16x32_f16(a, b[nt], acc[nt], 0, 0, 0);
    }

    #pragma unroll
    for (int nt=0; nt<5; ++nt) {
      int co = nt*16 + mr;
      float bv = bp[co];
      #pragma unroll
      for (int r=0; r<4; ++r) {
        int pq = wv*16 + quad*4 + r;       // tile-local position
        int rpp = (y0 + (pq>>3))*W + x0 + (pq&7);
        out[(b_*8400 + a0 + rpp)*85 + 5 + co] = sigm_f(acc[nt][r] + bv);
      }
    }
  } else {
    const _Float16* Bp = wbf + OFF_ROBJ + lvl*1536 + mr*96 + quad*8;
    float bv = (mr < 4) ? rb[lvl*4 + mr] : ((mr == 4) ? ob[lvl] : 0.f);
    float sc = (lvl==0) ? 8.f : (lvl==1 ? 16.f : 32.f);
    floatx4 acc = {0.f,0.f,0.f,0.f};
    #pragma unroll
    for (int k=0; k<3; ++k) {
      half8 a = *(const half8*)(ldsP + (wv*16 + mr)*PSTRIDE + k*32 + quad*8);
      half8 b = *(const half8*)(Bp + k*32);
      acc = __builtin_amdgcn_mfma_f32_16x16x32_f16(a, b, acc, 0, 0, 0);
    }
    #pragma unroll
    for (int r=0; r<4; ++r) {
      int pq = wv*16 + quad*4 + r;
      int yy = y0 + (pq>>3); int xx = x0 + (pq&7);
      int rpp = yy*W + xx;
      float v = acc[r] + bv;
      float o;
      if      (mr == 0) o = (v + (float)xx)*sc;
      else if (mr == 1) o = (v + (float)yy)*sc;
      else if (mr <  4) o = __expf(v)*sc;
      else              o = sigm_f(v);
      if (mr < 5)
        out[(b_*8400 + a0 + rpp)*85 + mr] = o;
    }
  }
}

extern "C" void kernel_launch(void* const* d_in, const int* in_sizes, int n_in,
                              void* d_out, int out_size, void* d_ws, size_t ws_size,
                              hipStream_t stream)
{
  bool dict = (in_sizes[1] == 96*128);
  const float* X[3]; const float* SW[3]; const float* SB[3];
  if (dict) {
    X[0]=(const float*)d_in[0]; SW[0]=(const float*)d_in[1]; SB[0]=(const float*)d_in[2];
    X[1]=(const float*)d_in[3]; SW[1]=(const float*)d_in[4]; SB[1]=(const float*)d_in[5];
    X[2]=(const float*)d_in[6]; SW[2]=(const float*)d_in[7]; SB[2]=(const float*)d_in[8];
  } else {
    X[0]=(const float*)d_in[0]; X[1]=(const float*)d_in[1]; X[2]=(const float*)d_in[2];
    SW[0]=(const float*)d_in[3]; SB[0]=(const float*)d_in[4];
    SW[1]=(const float*)d_in[5]; SB[1]=(const float*)d_in[6];
    SW[2]=(const float*)d_in[7]; SB[2]=(const float*)d_in[8];
  }
  const float* br_w1[2] = {(const float*)d_in[9],  (const float*)d_in[15]};
  const float* br_b1[2] = {(const float*)d_in[10], (const float*)d_in[16]};
  const float* br_wd[2] = {(const float*)d_in[11], (const float*)d_in[17]};
  const float* br_bd[2] = {(const float*)d_in[12], (const float*)d_in[18]};
  const float* br_w2[2] = {(const float*)d_in[13], (const float*)d_in[19]};
  const float* br_b2[2] = {(const float*)d_in[14], (const float*)d_in[20]};
  const float* clsp_w=(const float*)d_in[21]; const float* clsp_b=(const float*)d_in[22];
  const float* regp_w=(const float*)d_in[23]; const float* regp_b=(const float*)d_in[24];
  const float* objp_w=(const float*)d_in[25]; const float* objp_b=(const float*)d_in[26];

  float* out = (float*)d_out;

  // workspace (fp16 units): wbf 346,368 + stemO 12,902,400 = 26.5 MB
  _Float16* wbf   = (_Float16*)d_ws;
  _Float16* stemO = wbf + WTOT;

  // 1. weights/bias -> fp16 blob
  wconv_k<<<1353,256,0,stream>>>(SW[0],SW[1],SW[2],br_w1[0],br_w1[1],
                                 br_w2[0],br_w2[1],clsp_w,br_wd[0],br_wd[1],
                                 regp_w,objp_w,br_bd[0],br_bd[1],wbf);

  // 2. stem GEMM straight from NCHW fp32, channel-major output
  stem_k<<<1050,256,0,stream>>>(X[0],X[1],X[2],wbf,SB[0],SB[1],SB[2],stemO);

  // 3. MEGAFUSED expand + dw3x3 + project + residual + heads
  xfuse_k<<<dim3(2144,2),256,0,stream>>>(
      stemO, wbf, br_b1[0], br_b1[1], br_b2[0], br_b2[1],
      clsp_b, regp_b, objp_b, out);
}

// Round 19
// 182.083 us; speedup vs baseline: 1.0992x; 1.0992x over previous
//
#include <hip/hip_runtime.h>
#include <hip/hip_fp16.h>

typedef unsigned int uint32;
using half2v  = __attribute__((ext_vector_type(2))) _Float16;
using half4v  = __attribute__((ext_vector_type(4))) _Float16;
using half8   = __attribute__((ext_vector_type(8))) _Float16;
using floatx4 = __attribute__((ext_vector_type(4))) float;

__device__ __forceinline__ float sigm_f(float x){
  return __builtin_amdgcn_rcpf(1.0f + __expf(-x));
}
__device__ __forceinline__ float silu_f(float x){ return x * sigm_f(x); }

__device__ __forceinline__ half2v pkrtz(float a, float b){
  return __builtin_bit_cast(half2v, __builtin_amdgcn_cvt_pkrtz(a, b));
}

// packed fp16 silu: 2 elements; overflow is graceful (exp->inf->rcp->0).
__device__ __forceinline__ half2v silu_h2(half2v v){
  __half2 hv = __builtin_bit_cast(__half2, v);
  __half2 e  = h2exp(__hneg2(hv));
  __half2 r  = h2rcp(__hadd2(e, __float2half2_rn(1.0f)));
  return __builtin_bit_cast(half2v, __hmul2(hv, r));
}

// async global->LDS, 16B per lane, zero VGPR cost. dst is wave-uniform base;
// HW writes lane i at dst + i*16B. src is per-lane. Respects exec mask.
__device__ __forceinline__ void gll16(const _Float16* src, _Float16* ldsDst){
  __builtin_amdgcn_global_load_lds(
      (const __attribute__((address_space(1))) uint32*)src,
      (__attribute__((address_space(3))) uint32*)ldsDst, 16, 0, 0);
}

// ---------------------------------------------------------------------------
// fp16 weight blob layout (element offsets):
//   0      stemW0..2 | 86016 w1 (cls/reg) | 196608 w2 | 307200 clsp_w
//   330240 wdT | 340608 regobj | 345216 dwbias | 346368 total
// ---------------------------------------------------------------------------
#define OFF_W1    86016
#define OFF_W2    196608
#define OFF_HEAD  307200
#define OFF_WDT   330240
#define OFF_ROBJ  340608
#define OFF_DWB   345216
#define WTOT      346368

// stem output, CHANNEL-GROUP-MAJOR: [g=12][n=134400][8ch]
#define NDW  134400

__global__ __launch_bounds__(256) void wconv_k(
    const float* __restrict__ s0, const float* __restrict__ s1,
    const float* __restrict__ s2, const float* __restrict__ cw1,
    const float* __restrict__ rw1, const float* __restrict__ cw2,
    const float* __restrict__ rw2, const float* __restrict__ chw,
    const float* __restrict__ cwd, const float* __restrict__ rwd,
    const float* __restrict__ rpw, const float* __restrict__ opw,
    const float* __restrict__ cbd, const float* __restrict__ rbd,
    _Float16* __restrict__ dst)
{
  int i = blockIdx.x*256 + threadIdx.x;
  if (i >= WTOT) return;
  float v;
  if (i < OFF_WDT) {
    const float* p; int off;
    if      (i < 12288)  { p = s0;  off = i; }
    else if (i < 36864)  { p = s1;  off = i - 12288; }
    else if (i < 86016)  { p = s2;  off = i - 36864; }
    else if (i < 141312) { p = cw1; off = i - 86016; }
    else if (i < 196608) { p = rw1; off = i - 141312; }
    else if (i < 251904) { p = cw2; off = i - 196608; }
    else if (i < 307200) { p = rw2; off = i - 251904; }
    else                 { p = chw; off = i - 307200; }
    v = p[off];
  } else if (i < OFF_ROBJ) {
    int rel = i - OFF_WDT;
    int br = rel / 5184; int r2 = rel - br*5184;
    int lvl = r2 / 1728; int r3 = r2 - lvl*1728;
    int j = r3 / 192;    int c = r3 - j*192;
    const float* wd = br ? rwd : cwd;
    v = wd[lvl*1728 + c*9 + j];
  } else if (i < OFF_DWB) {
    int rel = i - OFF_ROBJ;
    int lvl = rel / 1536; int r2 = rel - lvl*1536;
    int co = r2 / 96;     int k = r2 - co*96;
    v = (co < 4) ? rpw[lvl*384 + co*96 + k] : (co == 4 ? opw[lvl*96 + k] : 0.f);
  } else {
    int rel = i - OFF_DWB;
    int br = rel / 576;  int r2 = rel - br*576;
    int lvl = r2 / 192;  int c = r2 - lvl*192;
    v = (br ? rbd : cbd)[lvl*192 + c];
  }
  dst[i] = (_Float16)v;
}

// ---------------------------------------------------------------------------
// Stem GEMM from NCHW fp32, fp16 MFMA. Output CHANNEL-GROUP-MAJOR [g][n][8].
// ---------------------------------------------------------------------------
__global__ __launch_bounds__(256) void stem_k(
    const float* __restrict__ x0, const float* __restrict__ x1,
    const float* __restrict__ x2, const _Float16* __restrict__ Wb,
    const float* __restrict__ sb0, const float* __restrict__ sb1,
    const float* __restrict__ sb2, _Float16* __restrict__ Out)
{
  const int m0 = blockIdx.x << 7;
  const int lvl = (m0 < 102400) ? 0 : (m0 < 128000 ? 1 : 2);
  const int CIN = (lvl==0)?128:(lvl==1?256:512);
  const int HW  = (lvl==0)?6400:(lvl==1?1600:400);
  const int noff= (lvl==0)?0:(lvl==1?102400:128000);
  const float* X = (lvl==0)?x0:(lvl==1?x1:x2);
  const _Float16* Wl = Wb + ((lvl==0)?0:(lvl==1?12288:36864));
  const float* bias = (lvl==0)?sb0:(lvl==1?sb1:sb2);

  int t=threadIdx.x, lane=t&63, wv=t>>6, mr=lane&15, quad=lane>>4;

  int idx[2];
  #pragma unroll
  for (int nt=0; nt<2; ++nt) {
    int n = m0 + wv*32 + nt*16 + mr;
    int m = n - noff; int b_ = m / HW; int p = m - b_*HW;
    idx[nt] = (b_*CIN + quad*8)*HW + p;
  }
  const _Float16* Ap = Wl + mr*CIN + quad*8;

  floatx4 zero = {0.f,0.f,0.f,0.f};
  floatx4 acc[6][2];
  #pragma unroll
  for (int i=0;i<6;++i)
    #pragma unroll
    for (int j=0;j<2;++j) acc[i][j] = zero;

  for (int k=0; k<CIN; k+=32) {
    half8 a[6], b[2];
    #pragma unroll
    for (int mt=0; mt<6; ++mt) a[mt] = *(const half8*)(Ap + mt*16*CIN);
    #pragma unroll
    for (int nt=0; nt<2; ++nt) {
      float f[8];
      #pragma unroll
      for (int j=0;j<8;++j) f[j] = X[idx[nt] + j*HW];
      half2v* bh = (half2v*)&b[nt];
      #pragma unroll
      for (int j=0;j<4;++j) bh[j] = pkrtz(f[2*j], f[2*j+1]);
    }
    #pragma unroll
    for (int mt=0; mt<6; ++mt)
      #pragma unroll
      for (int nt=0; nt<2; ++nt)
        acc[mt][nt] = __builtin_amdgcn_mfma_f32_16x16x32_f16(a[mt], b[nt], acc[mt][nt], 0, 0, 0);
    Ap += 32;
    #pragma unroll
    for (int nt=0; nt<2; ++nt) idx[nt] += 32*HW;
  }

  #pragma unroll
  for (int mt=0; mt<6; ++mt) {
    float4 bv = *(const float4*)(bias + mt*16 + quad*4);
    int co = mt*16 + quad*4;
    int g = co >> 3; int h = co & 7;
    #pragma unroll
    for (int nt=0; nt<2; ++nt) {
      int pos = m0 + wv*32 + nt*16 + mr;
      half4v o;
      o[0] = (_Float16)silu_f(acc[mt][nt][0] + bv.x);
      o[1] = (_Float16)silu_f(acc[mt][nt][1] + bv.y);
      o[2] = (_Float16)silu_f(acc[mt][nt][2] + bv.z);
      o[3] = (_Float16)silu_f(acc[mt][nt][3] + bv.w);
      *(half4v*)(Out + g*NDW*8 + pos*8 + h) = o;
    }
  }
}

// ---------------------------------------------------------------------------
// MEGAFUSED v4 (r17 config, best measured) + s_setprio around the k-loop.
//  - wdl: dw weights+bias staged once per block via zero-VGPR global_load_lds
//  - interleaved dw+proj k-loop (W2 loads overlap dw VALU chain)
//  - __launch_bounds__(256,3), LDS 42.7KB -> 3 blocks/CU; ldsP aliases halo
// grid (2144, 2): [0,1600) lvl0, [1600,2000) lvl1, [2000,2144) lvl2
// (overlapping 8x8 tiles on 20x20, y0,x0 in {0,6,12}; dup writes identical).
// ---------------------------------------------------------------------------
#define PSTRIDE 104
#define HS2 808
__global__ __launch_bounds__(256, 3) void xfuse_k(
    const _Float16* __restrict__ stemO, const _Float16* __restrict__ wbf,
    const float* __restrict__ b1c, const float* __restrict__ b1r,
    const float* __restrict__ b2_c, const float* __restrict__ b2_r,
    const float* __restrict__ hb, const float* __restrict__ rb,
    const float* __restrict__ ob, float* __restrict__ out)
{
  __shared__ _Float16 wdl[1984];         // dw weights [tap][192] | bias [192]
  __shared__ _Float16 halo[24*HS2];      // [g][100 entries][8ch] (+pad)
  _Float16* ldsP = halo;                 // alias after phase-2 barrier
  const int bz = blockIdx.y;
  const float* b2 = bz ? b2_r : b2_c;

  int orig = blockIdx.x;
  int bx = (orig & 7)*268 + (orig >> 3);   // bijective: 2144 = 8*268

  int lvl, W, HW, noff, a0;
  int b_, y0, x0;
  if (bx < 1600) {
    lvl = 0; W = 80; HW = 6400; noff = 0;      a0 = 0;
    b_ = bx / 100; int tl = bx - b_*100;
    y0 = (tl / 10) * 8; x0 = (tl - (tl/10)*10) * 8;
  } else if (bx < 2000) {
    lvl = 1; W = 40; HW = 1600; noff = 102400; a0 = 6400;
    int rel = bx - 1600; b_ = rel / 25; int tl = rel - b_*25;
    y0 = (tl / 5) * 8; x0 = (tl - (tl/5)*5) * 8;
  } else {
    lvl = 2; W = 20; HW = 400; noff = 128000; a0 = 8000;
    int rel = bx - 2000; b_ = rel / 9; int tl = rel - b_*9;
    int iy = tl / 3; int ix = tl - iy*3;
    y0 = iy*6; x0 = ix*6;                 // overlapping 8x8 tiles on 20x20
  }

  int t = threadIdx.x, lane = t & 63, wv = t >> 6;
  int mr = lane & 15, quad = lane >> 4;
  const int p = wv*16 + mr;              // this thread's tile-local position

  const _Float16* wT = wbf + OFF_WDT + bz*5184 + lvl*1728;
  const _Float16* bB = wbf + OFF_DWB + bz*576 + lvl*192;
  const _Float16* Ap = wbf + OFF_W2 + bz*55296 + lvl*18432 + mr*192 + quad*8;

  // ---- 0. stage dw weights+bias (1920 hw = 240 x 16B) into LDS, async ----
  {
    if (wv < 3) {
      gll16(wT + (wv*64 + lane)*8, wdl + wv*512);
    } else {
      if (lane < 24)
        gll16(wT + (192 + lane)*8, wdl + 1536);          // wdT chunks 192..215
      else if (lane < 48)
        gll16(bB + (lane - 24)*8, wdl + 1536);           // bias -> 1728..1919
    }
  }

  // this thread's global position n (center tile)
  const int n = noff + b_*HW + (y0 + (p>>3))*W + x0 + (p&7);

  // resid prefetch (consumed after phase 2)
  half4v rsv[6];
  #pragma unroll
  for (int mt=0; mt<6; ++mt) {
    int co = mt*16 + quad*4;
    int g = co >> 3; int h = co & 7;
    rsv[mt] = *(const half4v*)(stemO + g*(NDW*8) + n*8 + h);
  }

  // ---- 1. expand GEMM: W1 (reg-hoisted) x stem (direct global) -> halo ----
  {
    const _Float16* W1 = wbf + OFF_W1 + bz*55296 + lvl*18432;
    const float* bp1 = (bz ? b1r : b1c) + lvl*192;
    // hoist A-frags: 3 M-tiles x 3 k-steps
    half8 wf[3][3];
    #pragma unroll
    for (int m3 = 0; m3 < 3; ++m3)
      #pragma unroll
      for (int ks = 0; ks < 3; ++ks)
        wf[m3][ks] = *(const half8*)(W1 + ((wv*3+m3)*16 + mr)*96 + ks*32 + quad*8);

    #pragma unroll
    for (int nt = 0; nt < 7; ++nt) {
      int ee = nt*16 + mr;
      int e = ee < 100 ? ee : 99;
      int hy = e / 10, hx = e - hy*10;
      int ay = y0 - 1 + hy, ax = x0 - 1 + hx;
      bool oob = ((unsigned)ay >= (unsigned)W) || ((unsigned)ax >= (unsigned)W);
      int yy = ay < 0 ? 0 : (ay >= W ? W-1 : ay);
      int xx = ax < 0 ? 0 : (ax >= W ? W-1 : ax);
      int ne = noff + b_*HW + yy*W + xx;

      floatx4 acc[3];
      #pragma unroll
      for (int m3 = 0; m3 < 3; ++m3) acc[m3] = floatx4{0.f,0.f,0.f,0.f};
      #pragma unroll
      for (int ks = 0; ks < 3; ++ks) {
        half8 af = *(const half8*)(stemO + (ks*4+quad)*(NDW*8) + ne*8);
        #pragma unroll
        for (int m3 = 0; m3 < 3; ++m3)
          acc[m3] = __builtin_amdgcn_mfma_f32_16x16x32_f16(wf[m3][ks], af, acc[m3], 0, 0, 0);
      }
      if (ee < 100) {
        #pragma unroll
        for (int m3 = 0; m3 < 3; ++m3) {
          int co = (wv*3+m3)*16 + quad*4;
          float4 bv = *(const float4*)(bp1 + co);
          half4v o;
          if (oob) {
            o[0]=o[1]=o[2]=o[3]=(_Float16)0.f;
          } else {
            half2v p01 = silu_h2(pkrtz(acc[m3][0] + bv.x, acc[m3][1] + bv.y));
            half2v p23 = silu_h2(pkrtz(acc[m3][2] + bv.z, acc[m3][3] + bv.w));
            o[0]=p01[0]; o[1]=p01[1]; o[2]=p23[0]; o[3]=p23[1];
          }
          *(half4v*)(halo + (co>>3)*HS2 + ee*8 + (co&7)) = o;
        }
      }
    }
  }
  __syncthreads();   // halo complete + wdl staged (vmcnt drained)

  // ---- 2. fused dw + proj k-loop, taps + dw weights from LDS ----
  floatx4 pacc[6];
  #pragma unroll
  for (int j=0;j<6;++j) pacc[j] = floatx4{0.f,0.f,0.f,0.f};
  __builtin_amdgcn_s_setprio(1);
  {
    const int ty = p >> 3, tx = p & 7;
    const _Float16* hb0 = halo + (ty*10 + tx)*8;   // entry (ty,tx) base
    for (int k = 0; k < 6; ++k) {
      const int g = 4*k + quad;
      const _Float16* hg = hb0 + g*HS2;

      half8 a[9], w[9];
      #pragma unroll
      for (int dy = 0; dy < 3; ++dy)
        #pragma unroll
        for (int dx = 0; dx < 3; ++dx)
          a[dy*3+dx] = *(const half8*)(hg + (dy*10 + dx)*8);
      #pragma unroll
      for (int tap = 0; tap < 9; ++tap)
        w[tap] = *(const half8*)(wdl + tap*192 + g*8);
      half8 bv8 = *(const half8*)(wdl + 1728 + g*8);
      half8 wfp[6];
      #pragma unroll
      for (int mt = 0; mt < 6; ++mt)
        wfp[mt] = *(const half8*)(Ap + mt*16*192 + k*32);

      half2v ac0 = {bv8[0], bv8[1]};
      half2v ac1 = {bv8[2], bv8[3]};
      half2v ac2 = {bv8[4], bv8[5]};
      half2v ac3 = {bv8[6], bv8[7]};
      #pragma unroll
      for (int tap = 0; tap < 9; ++tap) {
        ac0 += half2v{a[tap][0],a[tap][1]} * half2v{w[tap][0],w[tap][1]};
        ac1 += half2v{a[tap][2],a[tap][3]} * half2v{w[tap][2],w[tap][3]};
        ac2 += half2v{a[tap][4],a[tap][5]} * half2v{w[tap][4],w[tap][5]};
        ac3 += half2v{a[tap][6],a[tap][7]} * half2v{w[tap][6],w[tap][7]};
      }
      half8 af;
      {
        half2v* oh = (half2v*)&af;
        oh[0] = silu_h2(ac0);
        oh[1] = silu_h2(ac1);
        oh[2] = silu_h2(ac2);
        oh[3] = silu_h2(ac3);
      }
      #pragma unroll
      for (int mt = 0; mt < 6; ++mt)
        pacc[mt] = __builtin_amdgcn_mfma_f32_16x16x32_f16(wfp[mt], af, pacc[mt], 0, 0, 0);
    }
  }
  __builtin_amdgcn_s_setprio(0);
  __syncthreads();   // halo reads done -> ldsP may overwrite

  // ---- 3. epilogue: + bias + prefetched residual -> ldsP [pos][co] ----
  {
    const float* bp2 = b2 + lvl*96;
    #pragma unroll
    for (int mt=0; mt<6; ++mt) {
      int co = mt*16 + quad*4;
      float4 bv = *(const float4*)(bp2 + co);
      half4v o;
      o[0] = (_Float16)(pacc[mt][0] + bv.x + (float)rsv[mt][0]);
      o[1] = (_Float16)(pacc[mt][1] + bv.y + (float)rsv[mt][1]);
      o[2] = (_Float16)(pacc[mt][2] + bv.z + (float)rsv[mt][2]);
      o[3] = (_Float16)(pacc[mt][3] + bv.w + (float)rsv[mt][3]);
      *(half4v*)(ldsP + p*PSTRIDE + co) = o;
    }
  }
  // heads read only this wave's 16 rows -> no barrier (same-wave ds ordering).

  // ---- heads ----
  if (bz == 0) {
    const _Float16* Bp = wbf + OFF_HEAD + lvl*7680 + mr*96 + quad*8;
    const float* bp = hb + lvl*80;
    floatx4 acc[5];
    #pragma unroll
    for (int j=0;j<5;++j) acc[j] = floatx4{0.f,0.f,0.f,0.f};

    #pragma unroll
    for (int k=0; k<3; ++k) {
      half8 a = *(const half8*)(ldsP + (wv*16 + mr)*PSTRIDE + k*32 + quad*8);
      half8 b[5];
      #pragma unroll
      for (int nt=0; nt<5; ++nt)
        b[nt] = *(const half8*)(Bp + nt*16*96 + k*32);
      #pragma unroll
      for (int nt=0; nt<5; ++nt)
        acc[nt] = __builtin_amdgcn_mfma_f32_16x16x32_f16(a, b[nt], acc[nt], 0, 0, 0);
    }

    #pragma unroll
    for (int nt=0; nt<5; ++nt) {
      int co = nt*16 + mr;
      float bv = bp[co];
      #pragma unroll
      for (int r=0; r<4; ++r) {
        int pq = wv*16 + quad*4 + r;       // tile-local position
        int rpp = (y0 + (pq>>3))*W + x0 + (pq&7);
        out[(b_*8400 + a0 + rpp)*85 + 5 + co] = sigm_f(acc[nt][r] + bv);
      }
    }
  } else {
    const _Float16* Bp = wbf + OFF_ROBJ + lvl*1536 + mr*96 + quad*8;
    float bv = (mr < 4) ? rb[lvl*4 + mr] : ((mr == 4) ? ob[lvl] : 0.f);
    float sc = (lvl==0) ? 8.f : (lvl==1 ? 16.f : 32.f);
    floatx4 acc = {0.f,0.f,0.f,0.f};
    #pragma unroll
    for (int k=0; k<3; ++k) {
      half8 a = *(const half8*)(ldsP + (wv*16 + mr)*PSTRIDE + k*32 + quad*8);
      half8 b = *(const half8*)(Bp + k*32);
      acc = __builtin_amdgcn_mfma_f32_16x16x32_f16(a, b, acc, 0, 0, 0);
    }
    #pragma unroll
    for (int r=0; r<4; ++r) {
      int pq = wv*16 + quad*4 + r;
      int yy = y0 + (pq>>3); int xx = x0 + (pq&7);
      int rpp = yy*W + xx;
      float v = acc[r] + bv;
      float o;
      if      (mr == 0) o = (v + (float)xx)*sc;
      else if (mr == 1) o = (v + (float)yy)*sc;
      else if (mr <  4) o = __expf(v)*sc;
      else              o = sigm_f(v);
      if (mr < 5)
        out[(b_*8400 + a0 + rpp)*85 + mr] = o;
    }
  }
}

extern "C" void kernel_launch(void* const* d_in, const int* in_sizes, int n_in,
                              void* d_out, int out_size, void* d_ws, size_t ws_size,
                              hipStream_t stream)
{
  bool dict = (in_sizes[1] == 96*128);
  const float* X[3]; const float* SW[3]; const float* SB[3];
  if (dict) {
    X[0]=(const float*)d_in[0]; SW[0]=(const float*)d_in[1]; SB[0]=(const float*)d_in[2];
    X[1]=(const float*)d_in[3]; SW[1]=(const float*)d_in[4]; SB[1]=(const float*)d_in[5];
    X[2]=(const float*)d_in[6]; SW[2]=(const float*)d_in[7]; SB[2]=(const float*)d_in[8];
  } else {
    X[0]=(const float*)d_in[0]; X[1]=(const float*)d_in[1]; X[2]=(const float*)d_in[2];
    SW[0]=(const float*)d_in[3]; SB[0]=(const float*)d_in[4];
    SW[1]=(const float*)d_in[5]; SB[1]=(const float*)d_in[6];
    SW[2]=(const float*)d_in[7]; SB[2]=(const float*)d_in[8];
  }
  const float* br_w1[2] = {(const float*)d_in[9],  (const float*)d_in[15]};
  const float* br_b1[2] = {(const float*)d_in[10], (const float*)d_in[16]};
  const float* br_wd[2] = {(const float*)d_in[11], (const float*)d_in[17]};
  const float* br_bd[2] = {(const float*)d_in[12], (const float*)d_in[18]};
  const float* br_w2[2] = {(const float*)d_in[13], (const float*)d_in[19]};
  const float* br_b2[2] = {(const float*)d_in[14], (const float*)d_in[20]};
  const float* clsp_w=(const float*)d_in[21]; const float* clsp_b=(const float*)d_in[22];
  const float* regp_w=(const float*)d_in[23]; const float* regp_b=(const float*)d_in[24];
  const float* objp_w=(const float*)d_in[25]; const float* objp_b=(const float*)d_in[26];

  float* out = (float*)d_out;

  // workspace (fp16 units): wbf 346,368 + stemO 12,902,400 = 26.5 MB
  _Float16* wbf   = (_Float16*)d_ws;
  _Float16* stemO = wbf + WTOT;

  // 1. weights/bias -> fp16 blob
  wconv_k<<<1353,256,0,stream>>>(SW[0],SW[1],SW[2],br_w1[0],br_w1[1],
                                 br_w2[0],br_w2[1],clsp_w,br_wd[0],br_wd[1],
                                 regp_w,objp_w,br_bd[0],br_bd[1],wbf);

  // 2. stem GEMM straight from NCHW fp32, channel-major output
  stem_k<<<1050,256,0,stream>>>(X[0],X[1],X[2],wbf,SB[0],SB[1],SB[2],stemO);

  // 3. MEGAFUSED expand + dw3x3 + project + residual + heads
  xfuse_k<<<dim3(2144,2),256,0,stream>>>(
      stemO, wbf, br_b1[0], br_b1[1], br_b2[0], br_b2[1],
      clsp_b, regp_b, objp_b, out);
}

// Round 20
// 180.474 us; speedup vs baseline: 1.1090x; 1.0089x over previous
//
#include <hip/hip_runtime.h>
#include <hip/hip_fp16.h>

typedef unsigned int uint32;
using half2v  = __attribute__((ext_vector_type(2))) _Float16;
using half4v  = __attribute__((ext_vector_type(4))) _Float16;
using half8   = __attribute__((ext_vector_type(8))) _Float16;
using floatx4 = __attribute__((ext_vector_type(4))) float;

__device__ __forceinline__ float sigm_f(float x){
  return __builtin_amdgcn_rcpf(1.0f + __expf(-x));
}
__device__ __forceinline__ float silu_f(float x){ return x * sigm_f(x); }

__device__ __forceinline__ half2v pkrtz(float a, float b){
  return __builtin_bit_cast(half2v, __builtin_amdgcn_cvt_pkrtz(a, b));
}

// packed fp16 silu: 2 elements; overflow is graceful (exp->inf->rcp->0).
__device__ __forceinline__ half2v silu_h2(half2v v){
  __half2 hv = __builtin_bit_cast(__half2, v);
  __half2 e  = h2exp(__hneg2(hv));
  __half2 r  = h2rcp(__hadd2(e, __float2half2_rn(1.0f)));
  return __builtin_bit_cast(half2v, __hmul2(hv, r));
}

// async global->LDS, 16B per lane, zero VGPR cost. dst is wave-uniform base;
// HW writes lane i at dst + i*16B. src is per-lane. Respects exec mask.
__device__ __forceinline__ void gll16(const _Float16* src, _Float16* ldsDst){
  __builtin_amdgcn_global_load_lds(
      (const __attribute__((address_space(1))) uint32*)src,
      (__attribute__((address_space(3))) uint32*)ldsDst, 16, 0, 0);
}

// ---------------------------------------------------------------------------
// fp16 weight blob layout (element offsets):
//   0      stemW0..2 | 86016 w1 (cls/reg) | 196608 w2 | 307200 clsp_w
//   330240 wdT | 340608 regobj | 345216 dwbias | 346368 total
// ---------------------------------------------------------------------------
#define OFF_W1    86016
#define OFF_W2    196608
#define OFF_HEAD  307200
#define OFF_WDT   330240
#define OFF_ROBJ  340608
#define OFF_DWB   345216
#define WTOT      346368

// stem output, CHANNEL-GROUP-MAJOR: [g=12][n=134400][8ch]
#define NDW  134400

__global__ __launch_bounds__(256) void wconv_k(
    const float* __restrict__ s0, const float* __restrict__ s1,
    const float* __restrict__ s2, const float* __restrict__ cw1,
    const float* __restrict__ rw1, const float* __restrict__ cw2,
    const float* __restrict__ rw2, const float* __restrict__ chw,
    const float* __restrict__ cwd, const float* __restrict__ rwd,
    const float* __restrict__ rpw, const float* __restrict__ opw,
    const float* __restrict__ cbd, const float* __restrict__ rbd,
    _Float16* __restrict__ dst)
{
  int i = blockIdx.x*256 + threadIdx.x;
  if (i >= WTOT) return;
  float v;
  if (i < OFF_WDT) {
    const float* p; int off;
    if      (i < 12288)  { p = s0;  off = i; }
    else if (i < 36864)  { p = s1;  off = i - 12288; }
    else if (i < 86016)  { p = s2;  off = i - 36864; }
    else if (i < 141312) { p = cw1; off = i - 86016; }
    else if (i < 196608) { p = rw1; off = i - 141312; }
    else if (i < 251904) { p = cw2; off = i - 196608; }
    else if (i < 307200) { p = rw2; off = i - 251904; }
    else                 { p = chw; off = i - 307200; }
    v = p[off];
  } else if (i < OFF_ROBJ) {
    int rel = i - OFF_WDT;
    int br = rel / 5184; int r2 = rel - br*5184;
    int lvl = r2 / 1728; int r3 = r2 - lvl*1728;
    int j = r3 / 192;    int c = r3 - j*192;
    const float* wd = br ? rwd : cwd;
    v = wd[lvl*1728 + c*9 + j];
  } else if (i < OFF_DWB) {
    int rel = i - OFF_ROBJ;
    int lvl = rel / 1536; int r2 = rel - lvl*1536;
    int co = r2 / 96;     int k = r2 - co*96;
    v = (co < 4) ? rpw[lvl*384 + co*96 + k] : (co == 4 ? opw[lvl*96 + k] : 0.f);
  } else {
    int rel = i - OFF_DWB;
    int br = rel / 576;  int r2 = rel - br*576;
    int lvl = r2 / 192;  int c = r2 - lvl*192;
    v = (br ? rbd : cbd)[lvl*192 + c];
  }
  dst[i] = (_Float16)v;
}

// ---------------------------------------------------------------------------
// Stem GEMM from NCHW fp32, fp16 MFMA. Output CHANNEL-GROUP-MAJOR [g][n][8].
// ---------------------------------------------------------------------------
__global__ __launch_bounds__(256) void stem_k(
    const float* __restrict__ x0, const float* __restrict__ x1,
    const float* __restrict__ x2, const _Float16* __restrict__ Wb,
    const float* __restrict__ sb0, const float* __restrict__ sb1,
    const float* __restrict__ sb2, _Float16* __restrict__ Out)
{
  const int m0 = blockIdx.x << 7;
  const int lvl = (m0 < 102400) ? 0 : (m0 < 128000 ? 1 : 2);
  const int CIN = (lvl==0)?128:(lvl==1?256:512);
  const int HW  = (lvl==0)?6400:(lvl==1?1600:400);
  const int noff= (lvl==0)?0:(lvl==1?102400:128000);
  const float* X = (lvl==0)?x0:(lvl==1?x1:x2);
  const _Float16* Wl = Wb + ((lvl==0)?0:(lvl==1?12288:36864));
  const float* bias = (lvl==0)?sb0:(lvl==1?sb1:sb2);

  int t=threadIdx.x, lane=t&63, wv=t>>6, mr=lane&15, quad=lane>>4;

  int idx[2];
  #pragma unroll
  for (int nt=0; nt<2; ++nt) {
    int n = m0 + wv*32 + nt*16 + mr;
    int m = n - noff; int b_ = m / HW; int p = m - b_*HW;
    idx[nt] = (b_*CIN + quad*8)*HW + p;
  }
  const _Float16* Ap = Wl + mr*CIN + quad*8;

  floatx4 zero = {0.f,0.f,0.f,0.f};
  floatx4 acc[6][2];
  #pragma unroll
  for (int i=0;i<6;++i)
    #pragma unroll
    for (int j=0;j<2;++j) acc[i][j] = zero;

  for (int k=0; k<CIN; k+=32) {
    half8 a[6], b[2];
    #pragma unroll
    for (int mt=0; mt<6; ++mt) a[mt] = *(const half8*)(Ap + mt*16*CIN);
    #pragma unroll
    for (int nt=0; nt<2; ++nt) {
      float f[8];
      #pragma unroll
      for (int j=0;j<8;++j) f[j] = X[idx[nt] + j*HW];
      half2v* bh = (half2v*)&b[nt];
      #pragma unroll
      for (int j=0;j<4;++j) bh[j] = pkrtz(f[2*j], f[2*j+1]);
    }
    #pragma unroll
    for (int mt=0; mt<6; ++mt)
      #pragma unroll
      for (int nt=0; nt<2; ++nt)
        acc[mt][nt] = __builtin_amdgcn_mfma_f32_16x16x32_f16(a[mt], b[nt], acc[mt][nt], 0, 0, 0);
    Ap += 32;
    #pragma unroll
    for (int nt=0; nt<2; ++nt) idx[nt] += 32*HW;
  }

  #pragma unroll
  for (int mt=0; mt<6; ++mt) {
    float4 bv = *(const float4*)(bias + mt*16 + quad*4);
    int co = mt*16 + quad*4;
    int g = co >> 3; int h = co & 7;
    #pragma unroll
    for (int nt=0; nt<2; ++nt) {
      int pos = m0 + wv*32 + nt*16 + mr;
      half4v o;
      o[0] = (_Float16)silu_f(acc[mt][nt][0] + bv.x);
      o[1] = (_Float16)silu_f(acc[mt][nt][1] + bv.y);
      o[2] = (_Float16)silu_f(acc[mt][nt][2] + bv.z);
      o[3] = (_Float16)silu_f(acc[mt][nt][3] + bv.w);
      *(half4v*)(Out + g*NDW*8 + pos*8 + h) = o;
    }
  }
}

// ---------------------------------------------------------------------------
// MEGAFUSED v6 = r19 (best measured) + setprio window extended over the
// expand-phase MFMA section (same mechanism that paid in the k-loop).
//  - wdl: dw weights+bias staged once per block via zero-VGPR global_load_lds
//  - interleaved dw+proj k-loop (W2 loads overlap dw VALU chain)
//  - __launch_bounds__(256,3), LDS 42.7KB -> 3 blocks/CU; ldsP aliases halo
// grid (2144, 2): [0,1600) lvl0, [1600,2000) lvl1, [2000,2144) lvl2
// (overlapping 8x8 tiles on 20x20, y0,x0 in {0,6,12}; dup writes identical).
// ---------------------------------------------------------------------------
#define PSTRIDE 104
#define HS2 808
__global__ __launch_bounds__(256, 3) void xfuse_k(
    const _Float16* __restrict__ stemO, const _Float16* __restrict__ wbf,
    const float* __restrict__ b1c, const float* __restrict__ b1r,
    const float* __restrict__ b2_c, const float* __restrict__ b2_r,
    const float* __restrict__ hb, const float* __restrict__ rb,
    const float* __restrict__ ob, float* __restrict__ out)
{
  __shared__ _Float16 wdl[1984];         // dw weights [tap][192] | bias [192]
  __shared__ _Float16 halo[24*HS2];      // [g][100 entries][8ch] (+pad)
  _Float16* ldsP = halo;                 // alias after phase-2 barrier
  const int bz = blockIdx.y;
  const float* b2 = bz ? b2_r : b2_c;

  int orig = blockIdx.x;
  int bx = (orig & 7)*268 + (orig >> 3);   // bijective: 2144 = 8*268

  int lvl, W, HW, noff, a0;
  int b_, y0, x0;
  if (bx < 1600) {
    lvl = 0; W = 80; HW = 6400; noff = 0;      a0 = 0;
    b_ = bx / 100; int tl = bx - b_*100;
    y0 = (tl / 10) * 8; x0 = (tl - (tl/10)*10) * 8;
  } else if (bx < 2000) {
    lvl = 1; W = 40; HW = 1600; noff = 102400; a0 = 6400;
    int rel = bx - 1600; b_ = rel / 25; int tl = rel - b_*25;
    y0 = (tl / 5) * 8; x0 = (tl - (tl/5)*5) * 8;
  } else {
    lvl = 2; W = 20; HW = 400; noff = 128000; a0 = 8000;
    int rel = bx - 2000; b_ = rel / 9; int tl = rel - b_*9;
    int iy = tl / 3; int ix = tl - iy*3;
    y0 = iy*6; x0 = ix*6;                 // overlapping 8x8 tiles on 20x20
  }

  int t = threadIdx.x, lane = t & 63, wv = t >> 6;
  int mr = lane & 15, quad = lane >> 4;
  const int p = wv*16 + mr;              // this thread's tile-local position

  const _Float16* wT = wbf + OFF_WDT + bz*5184 + lvl*1728;
  const _Float16* bB = wbf + OFF_DWB + bz*576 + lvl*192;
  const _Float16* Ap = wbf + OFF_W2 + bz*55296 + lvl*18432 + mr*192 + quad*8;

  // ---- 0. stage dw weights+bias (1920 hw = 240 x 16B) into LDS, async ----
  {
    if (wv < 3) {
      gll16(wT + (wv*64 + lane)*8, wdl + wv*512);
    } else {
      if (lane < 24)
        gll16(wT + (192 + lane)*8, wdl + 1536);          // wdT chunks 192..215
      else if (lane < 48)
        gll16(bB + (lane - 24)*8, wdl + 1536);           // bias -> 1728..1919
    }
  }

  // this thread's global position n (center tile)
  const int n = noff + b_*HW + (y0 + (p>>3))*W + x0 + (p&7);

  // resid prefetch (consumed after phase 2)
  half4v rsv[6];
  #pragma unroll
  for (int mt=0; mt<6; ++mt) {
    int co = mt*16 + quad*4;
    int g = co >> 3; int h = co & 7;
    rsv[mt] = *(const half4v*)(stemO + g*(NDW*8) + n*8 + h);
  }

  // ---- 1. expand GEMM: W1 (reg-hoisted) x stem (direct global) -> halo ----
  {
    const _Float16* W1 = wbf + OFF_W1 + bz*55296 + lvl*18432;
    const float* bp1 = (bz ? b1r : b1c) + lvl*192;
    // hoist A-frags: 3 M-tiles x 3 k-steps
    half8 wf[3][3];
    #pragma unroll
    for (int m3 = 0; m3 < 3; ++m3)
      #pragma unroll
      for (int ks = 0; ks < 3; ++ks)
        wf[m3][ks] = *(const half8*)(W1 + ((wv*3+m3)*16 + mr)*96 + ks*32 + quad*8);

    __builtin_amdgcn_s_setprio(1);
    #pragma unroll
    for (int nt = 0; nt < 7; ++nt) {
      int ee = nt*16 + mr;
      int e = ee < 100 ? ee : 99;
      int hy = e / 10, hx = e - hy*10;
      int ay = y0 - 1 + hy, ax = x0 - 1 + hx;
      bool oob = ((unsigned)ay >= (unsigned)W) || ((unsigned)ax >= (unsigned)W);
      int yy = ay < 0 ? 0 : (ay >= W ? W-1 : ay);
      int xx = ax < 0 ? 0 : (ax >= W ? W-1 : ax);
      int ne = noff + b_*HW + yy*W + xx;

      floatx4 acc[3];
      #pragma unroll
      for (int m3 = 0; m3 < 3; ++m3) acc[m3] = floatx4{0.f,0.f,0.f,0.f};
      #pragma unroll
      for (int ks = 0; ks < 3; ++ks) {
        half8 af = *(const half8*)(stemO + (ks*4+quad)*(NDW*8) + ne*8);
        #pragma unroll
        for (int m3 = 0; m3 < 3; ++m3)
          acc[m3] = __builtin_amdgcn_mfma_f32_16x16x32_f16(wf[m3][ks], af, acc[m3], 0, 0, 0);
      }
      if (ee < 100) {
        #pragma unroll
        for (int m3 = 0; m3 < 3; ++m3) {
          int co = (wv*3+m3)*16 + quad*4;
          float4 bv = *(const float4*)(bp1 + co);
          half4v o;
          if (oob) {
            o[0]=o[1]=o[2]=o[3]=(_Float16)0.f;
          } else {
            half2v p01 = silu_h2(pkrtz(acc[m3][0] + bv.x, acc[m3][1] + bv.y));
            half2v p23 = silu_h2(pkrtz(acc[m3][2] + bv.z, acc[m3][3] + bv.w));
            o[0]=p01[0]; o[1]=p01[1]; o[2]=p23[0]; o[3]=p23[1];
          }
          *(half4v*)(halo + (co>>3)*HS2 + ee*8 + (co&7)) = o;
        }
      }
    }
    __builtin_amdgcn_s_setprio(0);
  }
  __syncthreads();   // halo complete + wdl staged (vmcnt drained)

  // ---- 2. fused dw + proj k-loop, taps + dw weights from LDS ----
  floatx4 pacc[6];
  #pragma unroll
  for (int j=0;j<6;++j) pacc[j] = floatx4{0.f,0.f,0.f,0.f};
  __builtin_amdgcn_s_setprio(1);
  {
    const int ty = p >> 3, tx = p & 7;
    const _Float16* hb0 = halo + (ty*10 + tx)*8;   // entry (ty,tx) base
    for (int k = 0; k < 6; ++k) {
      const int g = 4*k + quad;
      const _Float16* hg = hb0 + g*HS2;

      half8 a[9], w[9];
      #pragma unroll
      for (int dy = 0; dy < 3; ++dy)
        #pragma unroll
        for (int dx = 0; dx < 3; ++dx)
          a[dy*3+dx] = *(const half8*)(hg + (dy*10 + dx)*8);
      #pragma unroll
      for (int tap = 0; tap < 9; ++tap)
        w[tap] = *(const half8*)(wdl + tap*192 + g*8);
      half8 bv8 = *(const half8*)(wdl + 1728 + g*8);
      half8 wfp[6];
      #pragma unroll
      for (int mt = 0; mt < 6; ++mt)
        wfp[mt] = *(const half8*)(Ap + mt*16*192 + k*32);

      half2v ac0 = {bv8[0], bv8[1]};
      half2v ac1 = {bv8[2], bv8[3]};
      half2v ac2 = {bv8[4], bv8[5]};
      half2v ac3 = {bv8[6], bv8[7]};
      #pragma unroll
      for (int tap = 0; tap < 9; ++tap) {
        ac0 += half2v{a[tap][0],a[tap][1]} * half2v{w[tap][0],w[tap][1]};
        ac1 += half2v{a[tap][2],a[tap][3]} * half2v{w[tap][2],w[tap][3]};
        ac2 += half2v{a[tap][4],a[tap][5]} * half2v{w[tap][4],w[tap][5]};
        ac3 += half2v{a[tap][6],a[tap][7]} * half2v{w[tap][6],w[tap][7]};
      }
      half8 af;
      {
        half2v* oh = (half2v*)&af;
        oh[0] = silu_h2(ac0);
        oh[1] = silu_h2(ac1);
        oh[2] = silu_h2(ac2);
        oh[3] = silu_h2(ac3);
      }
      #pragma unroll
      for (int mt = 0; mt < 6; ++mt)
        pacc[mt] = __builtin_amdgcn_mfma_f32_16x16x32_f16(wfp[mt], af, pacc[mt], 0, 0, 0);
    }
  }
  __builtin_amdgcn_s_setprio(0);
  __syncthreads();   // halo reads done -> ldsP may overwrite

  // ---- 3. epilogue: + bias + prefetched residual -> ldsP [pos][co] ----
  {
    const float* bp2 = b2 + lvl*96;
    #pragma unroll
    for (int mt=0; mt<6; ++mt) {
      int co = mt*16 + quad*4;
      float4 bv = *(const float4*)(bp2 + co);
      half4v o;
      o[0] = (_Float16)(pacc[mt][0] + bv.x + (float)rsv[mt][0]);
      o[1] = (_Float16)(pacc[mt][1] + bv.y + (float)rsv[mt][1]);
      o[2] = (_Float16)(pacc[mt][2] + bv.z + (float)rsv[mt][2]);
      o[3] = (_Float16)(pacc[mt][3] + bv.w + (float)rsv[mt][3]);
      *(half4v*)(ldsP + p*PSTRIDE + co) = o;
    }
  }
  // heads read only this wave's 16 rows -> no barrier (same-wave ds ordering).

  // ---- heads ----
  if (bz == 0) {
    const _Float16* Bp = wbf + OFF_HEAD + lvl*7680 + mr*96 + quad*8;
    const float* bp = hb + lvl*80;
    floatx4 acc[5];
    #pragma unroll
    for (int j=0;j<5;++j) acc[j] = floatx4{0.f,0.f,0.f,0.f};

    #pragma unroll
    for (int k=0; k<3; ++k) {
      half8 a = *(const half8*)(ldsP + (wv*16 + mr)*PSTRIDE + k*32 + quad*8);
      half8 b[5];
      #pragma unroll
      for (int nt=0; nt<5; ++nt)
        b[nt] = *(const half8*)(Bp + nt*16*96 + k*32);
      #pragma unroll
      for (int nt=0; nt<5; ++nt)
        acc[nt] = __builtin_amdgcn_mfma_f32_16x16x32_f16(a, b[nt], acc[nt], 0, 0, 0);
    }

    #pragma unroll
    for (int nt=0; nt<5; ++nt) {
      int co = nt*16 + mr;
      float bv = bp[co];
      #pragma unroll
      for (int r=0; r<4; ++r) {
        int pq = wv*16 + quad*4 + r;       // tile-local position
        int rpp = (y0 + (pq>>3))*W + x0 + (pq&7);
        out[(b_*8400 + a0 + rpp)*85 + 5 + co] = sigm_f(acc[nt][r] + bv);
      }
    }
  } else {
    const _Float16* Bp = wbf + OFF_ROBJ + lvl*1536 + mr*96 + quad*8;
    float bv = (mr < 4) ? rb[lvl*4 + mr] : ((mr == 4) ? ob[lvl] : 0.f);
    float sc = (lvl==0) ? 8.f : (lvl==1 ? 16.f : 32.f);
    floatx4 acc = {0.f,0.f,0.f,0.f};
    #pragma unroll
    for (int k=0; k<3; ++k) {
      half8 a = *(const half8*)(ldsP + (wv*16 + mr)*PSTRIDE + k*32 + quad*8);
      half8 b = *(const half8*)(Bp + k*32);
      acc = __builtin_amdgcn_mfma_f32_16x16x32_f16(a, b, acc, 0, 0, 0);
    }
    #pragma unroll
    for (int r=0; r<4; ++r) {
      int pq = wv*16 + quad*4 + r;
      int yy = y0 + (pq>>3); int xx = x0 + (pq&7);
      int rpp = yy*W + xx;
      float v = acc[r] + bv;
      float o;
      if      (mr == 0) o = (v + (float)xx)*sc;
      else if (mr == 1) o = (v + (float)yy)*sc;
      else if (mr <  4) o = __expf(v)*sc;
      else              o = sigm_f(v);
      if (mr < 5)
        out[(b_*8400 + a0 + rpp)*85 + mr] = o;
    }
  }
}

extern "C" void kernel_launch(void* const* d_in, const int* in_sizes, int n_in,
                              void* d_out, int out_size, void* d_ws, size_t ws_size,
                              hipStream_t stream)
{
  bool dict = (in_sizes[1] == 96*128);
  const float* X[3]; const float* SW[3]; const float* SB[3];
  if (dict) {
    X[0]=(const float*)d_in[0]; SW[0]=(const float*)d_in[1]; SB[0]=(const float*)d_in[2];
    X[1]=(const float*)d_in[3]; SW[1]=(const float*)d_in[4]; SB[1]=(const float*)d_in[5];
    X[2]=(const float*)d_in[6]; SW[2]=(const float*)d_in[7]; SB[2]=(const float*)d_in[8];
  } else {
    X[0]=(const float*)d_in[0]; X[1]=(const float*)d_in[1]; X[2]=(const float*)d_in[2];
    SW[0]=(const float*)d_in[3]; SB[0]=(const float*)d_in[4];
    SW[1]=(const float*)d_in[5]; SB[1]=(const float*)d_in[6];
    SW[2]=(const float*)d_in[7]; SB[2]=(const float*)d_in[8];
  }
  const float* br_w1[2] = {(const float*)d_in[9],  (const float*)d_in[15]};
  const float* br_b1[2] = {(const float*)d_in[10], (const float*)d_in[16]};
  const float* br_wd[2] = {(const float*)d_in[11], (const float*)d_in[17]};
  const float* br_bd[2] = {(const float*)d_in[12], (const float*)d_in[18]};
  const float* br_w2[2] = {(const float*)d_in[13], (const float*)d_in[19]};
  const float* br_b2[2] = {(const float*)d_in[14], (const float*)d_in[20]};
  const float* clsp_w=(const float*)d_in[21]; const float* clsp_b=(const float*)d_in[22];
  const float* regp_w=(const float*)d_in[23]; const float* regp_b=(const float*)d_in[24];
  const float* objp_w=(const float*)d_in[25]; const float* objp_b=(const float*)d_in[26];

  float* out = (float*)d_out;

  // workspace (fp16 units): wbf 346,368 + stemO 12,902,400 = 26.5 MB
  _Float16* wbf   = (_Float16*)d_ws;
  _Float16* stemO = wbf + WTOT;

  // 1. weights/bias -> fp16 blob
  wconv_k<<<1353,256,0,stream>>>(SW[0],SW[1],SW[2],br_w1[0],br_w1[1],
                                 br_w2[0],br_w2[1],clsp_w,br_wd[0],br_wd[1],
                                 regp_w,objp_w,br_bd[0],br_bd[1],wbf);

  // 2. stem GEMM straight from NCHW fp32, channel-major output
  stem_k<<<1050,256,0,stream>>>(X[0],X[1],X[2],wbf,SB[0],SB[1],SB[2],stemO);

  // 3. MEGAFUSED expand + dw3x3 + project + residual + heads
  xfuse_k<<<dim3(2144,2),256,0,stream>>>(
      stemO, wbf, br_b1[0], br_b1[1], br_b2[0], br_b2[1],
      clsp_b, regp_b, objp_b, out);
}